// Round 2
// baseline (735.929 us; speedup 1.0000x reference)
//
#include <hip/hip_runtime.h>

// GRU fused, round 8: 3-wave gate-split (round-7 resubmit; infra failed).
// Round 6 forensics: ~266 dynamic VALU inst/step/wave vs ~110 in source at
// 88 VGPRs for a ~135-dword live set (81 dwords = per-lane weights) ->
// allocator copy bloat; plus per-step exposed global-load latency on the x
// prefetch. Restructure: one batch per 192-thread block, wave g owns gate g
// (r/z/n). Per-lane weights 81->27 dwords, occupancy 2->6 waves/SIMD, x
// staged per 8-step window through LDS with lgkm-only barriers so global
// loads span barriers. Change vs round 7: waves_per_eu(6) min-only.

typedef __fp16 h2_t __attribute__((ext_vector_type(2)));

namespace {

constexpr int T = 1024;
constexpr int D = 6;
constexpr int H = 48;
constexpr int W = 8;              // h-history window (fused FC + x staging)

__device__ __forceinline__ float fexp2(float x) { return __builtin_amdgcn_exp2f(x); }
__device__ __forceinline__ float frcp(float x) { return __builtin_amdgcn_rcpf(x); }
__device__ __forceinline__ float sigmoid_f(float x) {
  return frcp(1.0f + fexp2(-1.44269504088896340736f * x));
}
__device__ __forceinline__ float tanh_f(float x) {
  float e = fexp2(2.88539008177792681472f * x);
  return 1.0f - 2.0f * frcp(e + 1.0f);
}
__device__ __forceinline__ h2_t pk(float a, float b) {
  return __builtin_amdgcn_cvt_pkrtz(a, b);
}
__device__ __forceinline__ float fdot2(h2_t a, h2_t b, float c) {
  return __builtin_amdgcn_fdot2(a, b, c, false);
}
__device__ __forceinline__ h2_t bc(unsigned v) {
  union { unsigned u; h2_t h; } x; x.u = v; return x.h;
}
__device__ __forceinline__ unsigned as_u(h2_t v) {
  union { h2_t h; unsigned u; } x; x.h = v; return x.u;
}
// Block barrier that drains LDS only: pending global loads (x prefetch,
// y stores) stay in flight across it, unlike __syncthreads' vmcnt(0) drain.
__device__ __forceinline__ void bar_lgkm() {
  asm volatile("s_waitcnt lgkmcnt(0)\n\ts_barrier" ::: "memory");
}

__global__ __launch_bounds__(192)
__attribute__((amdgpu_waves_per_eu(6)))
void gru_fused3(
    const float* __restrict__ x, const float* __restrict__ W_ih,
    const float* __restrict__ W_hh, const float* __restrict__ b_ih,
    const float* __restrict__ b_hh, const float* __restrict__ fc_w,
    const float* __restrict__ fc_b, float* __restrict__ y) {

  // h history: 8 slots, stride 28 dwords (24 f16-pairs + 4 pad) so the FC
  // phase's 8 slot-groups land on disjoint bank quads. Recurrence reads are
  // wave-uniform broadcasts (conflict-free).
  __shared__ uint4 h2s[W][7];
  __shared__ uint4 fcw2s[D][7];    // fc_w rows packed f16, padded stride
  __shared__ float rzbuf[48][2];   // cooked r (col 0) and z (col 1), f32
  __shared__ __align__(16) unsigned xbuf[2][32];  // [buf][step*4+c] packed x

  const int tid  = threadIdx.x;
  const int wid  = tid >> 6;       // 0=r, 1=z, 2=n+combine
  const int lane = tid & 63;
  const int u    = (lane < 48) ? lane : 47;   // clamp idle lanes
  const bool active = (lane < 48);
  const int row = u + wid * H;     // this wave's gate row for unit u

  // ---- init: LDS zero/pack (all threads) ----
  for (int i = tid; i < W * 28; i += 192) ((unsigned*)&h2s[0][0])[i] = 0u;
  for (int i = tid; i < D * 24; i += 192) {
    const int d = i / 24, j = i - d * 24;
    const float2 w = ((const float2*)(fc_w + d * H))[j];
    ((h2_t*)&fcw2s[d][0])[j] = pk(w.x, w.y);
  }

  // ---- per-lane weights: ONE gate row of W_hh (24 dw) + W_ih (3 dw) ----
  h2_t wh2[24], wi2[3];
  {
    const float2* rr = (const float2*)(W_hh + row * H);
#pragma unroll
    for (int j = 0; j < 24; ++j) wh2[j] = pk(rr[j].x, rr[j].y);
    const float2* ri = (const float2*)(W_ih + row * D);
#pragma unroll
    for (int j = 0; j < 3; ++j) wi2[j] = pk(ri[j].x, ri[j].y);
  }
  const float bih = b_ih[row], bhh = b_hh[row];
  // waves 0/1: preact = (gh+b_hh) + (gi+b_ih); wave 2 keeps gi and gh
  // separate (n = tanh(gi + r*gh), b_hh inside the r-multiply).
  const float acc0 = (wid == 2) ? bhh : (bih + bhh);
  const float gi0  = (wid == 2) ? bih : 0.0f;

  const size_t batch = blockIdx.x;
  const float2* xpp = (const float2*)(x + batch * (size_t)T * D);
  unsigned* xw = &xbuf[0][0];

  // x staging lanes (wave1): lane = step*4 + c, c<3 -> float2 (2 of 6 floats)
  const int xs = lane >> 2, xc = lane & 3;
  const bool xact = (wid == 1) && (lane < 32) && (xc < 3);

  // FC mapping (wave0): lanes 0..47 = 8 timesteps x 6 outputs
  const int yts = u / D, yd = u - yts * D;
  const float fcb = fc_b[yd];
  float* ybase = y + (batch * (size_t)T + yts) * D + yd;

  // prologue: stage window 0 of x
  if (xact) {
    const float2 v0 = xpp[xs * 3 + xc];
    xw[xs * 4 + xc] = as_u(pk(v0.x, v0.y));
  }
  __syncthreads();

  float hreg = 0.0f;               // live state in wave2 only

  for (int t0 = 0; t0 < T; t0 += W) {
    const int rb = (t0 >> 3) & 1;
    // issue next window's x loads now; vmcnt wait only at the commit at tw==7
    float2 nvx;
    if (xact) {
      int tl = t0 + W + xs; tl = (tl < T) ? tl : (T - 1);
      nvx = xpp[tl * 3 + xc];
    }

#pragma unroll
    for (int tw = 0; tw < W; ++tw) {
      const int p = (tw + W - 1) & (W - 1);

      // broadcast reads: h[t-1] (6xb128) + this step's packed x (1xb128)
      const uint4* hv = &h2s[p][0];
      const uint4 h0 = hv[0], h1 = hv[1], h2v = hv[2];
      const uint4 h3 = hv[3], h4 = hv[4], h5 = hv[5];
      const uint4 xq = *(const uint4*)&xw[rb * 32 + tw * 4];

      // gi chain (covers h ds_read latency)
      float gg = fdot2(wi2[0], bc(xq.x), gi0);
      gg = fdot2(wi2[1], bc(xq.y), gg);
      gg = fdot2(wi2[2], bc(xq.z), gg);

      // this gate's recurrent dot: 24 fdot2, 2 chains
      float aa = acc0, bb = 0.0f;
#define DOT4(hq, q)                                    \
      aa = fdot2(wh2[4*(q)+0], bc((hq).x), aa);        \
      bb = fdot2(wh2[4*(q)+1], bc((hq).y), bb);        \
      aa = fdot2(wh2[4*(q)+2], bc((hq).z), aa);        \
      bb = fdot2(wh2[4*(q)+3], bc((hq).w), bb);
      DOT4(h0, 0) DOT4(h1, 1) DOT4(h2v, 2)
      DOT4(h3, 3) DOT4(h4, 4) DOT4(h5, 5)
#undef DOT4

      if (wid != 2) {
        const float g = sigmoid_f(aa + bb + gg);
        if (active) rzbuf[u][wid] = g;
      }
      bar_lgkm();                  // r,z visible to wave2

      if (wid == 2) {
        const float2 rz = *(const float2*)&rzbuf[u][0];
        const float n = tanh_f(fmaf(rz.x, aa + bb, gg));
        hreg = fmaf(rz.y, hreg - n, n);    // (1-z)n + z h
        if (active) ((__fp16*)&h2s[tw][0])[u] = (__fp16)hreg;
      } else if (tw == W - 1) {
        // wave1 idle slot: commit next window's x (vmcnt waits here, ~7
        // steps after issue -> fully covered)
        if (xact) xw[(rb ^ 1) * 32 + xs * 4 + xc] = as_u(pk(nvx.x, nvx.y));
      }
      bar_lgkm();                  // h[t] (and staged x) visible to all
    }

    // fused FC over the window: wave0 only. Safe vs the next window's h2s
    // writes: wave2 writes h2s only after the next step's first barrier,
    // which wave0 reaches only after finishing the FC.
    if (wid == 0 && active) {
      const uint4* hv = &h2s[yts][0];
      const uint4* fv = &fcw2s[yd][0];
      float f0 = fcb, f1 = 0.0f;
#pragma unroll
      for (int j = 0; j < 6; ++j) {
        const uint4 hh = hv[j], ww = fv[j];
        f0 = fdot2(bc(hh.x), bc(ww.x), f0);
        f1 = fdot2(bc(hh.y), bc(ww.y), f1);
        f0 = fdot2(bc(hh.z), bc(ww.z), f0);
        f1 = fdot2(bc(hh.w), bc(ww.w), f1);
      }
      ybase[t0 * D] = f0 + f1;
    }
  }
}

}  // namespace

extern "C" void kernel_launch(void* const* d_in, const int* in_sizes, int n_in,
                              void* d_out, int out_size, void* d_ws, size_t ws_size,
                              hipStream_t stream) {
  const float* x    = (const float*)d_in[0];
  const float* W_ih = (const float*)d_in[1];
  const float* W_hh = (const float*)d_in[2];
  const float* b_ih = (const float*)d_in[3];
  const float* b_hh = (const float*)d_in[4];
  const float* fc_w = (const float*)d_in[5];
  const float* fc_b = (const float*)d_in[6];
  float* y = (float*)d_out;

  constexpr int B = 2048;
  gru_fused3<<<B, 192, 0, stream>>>(x, W_ih, W_hh, b_ih, b_hh, fc_w, fc_b, y);
}